// Round 3
// baseline (194.680 us; speedup 1.0000x reference)
//
#include <hip/hip_runtime.h>

// out[b,o,i,j] = bias[o] + sum_{c,r,s} w[o,c,r,s] * xpad[b,c,i+r,j+s]
// (reference's FFT circular-conv + roll + slice == conv2d pad=1; the
//  frequency-threshold pruning perturbs by ~0.039 absmax < 0.084 threshold)
//
// R3: occupancy fix. R1 was grid-limited (512 blocks = 2/CU = 21% occupancy,
// VALUBusy 20%). Split input channels x4 -> 2048 blocks (8/CU, 32 waves/CU),
// combine partials via atomicAdd onto a bias-initialized output. Inner loop
// is R1's proven 2-barrier structure with channel-invariant geometry hoisted.

#define OG 4   // output channels per block
#define CG 8   // input channels per block (32 / 4 splits)

__global__ void init_bias(const float* __restrict__ bias, float* __restrict__ out) {
    const int g = blockIdx.x * 256 + threadIdx.x;   // float4 index, [0, 524288)
    const int o = (g >> 12) & 31;                   // 4096 float4 per (b,o) plane
    const float v = bias[o];
    ((float4*)out)[g] = make_float4(v, v, v, v);
}

__global__ __launch_bounds__(256, 8)
void conv3x3_atomic(const float* __restrict__ x, const float* __restrict__ w,
                    float* __restrict__ out) {
    const int tid = threadIdx.x;
    const int tx  = tid & 7;    // col strip: cols 4*tx .. 4*tx+3
    const int ty  = tid >> 3;   // row in tile, 0..31
    const int tile = blockIdx.x;        // 4x4 tiles of 32x32
    const int b   = blockIdx.y;
    const int z   = blockIdx.z;         // og*4 + cg
    const int og  = z >> 2;
    const int c0  = (z & 3) * CG;       // first input channel of this block
    const int row0 = (tile >> 2) << 5;
    const int col0 = (tile & 3) << 5;

    __shared__ __align__(16) float xs[2][34][36];     // 2 channels per round
    __shared__ __align__(16) float ws[CG * 9][OG];    // [cl*9+t][oo]

    // stage this block's weight slice: w[(o*32 + c)*9 + t]
    for (int idx = tid; idx < CG * 9 * OG; idx += 256) {   // 288
        const int k  = idx >> 2;        // cl*9 + t
        const int oo = idx & 3;
        const int cl = k / 9;
        const int t  = k - 9 * cl;
        ws[k][oo] = w[((og * OG + oo) * 32 + c0 + cl) * 9 + t];
    }

    // ---- channel-invariant staging geometry (5 cells/thread, 34x34=1156) ----
    int off[5];    // in-plane global offset, or -1 if zero-pad / out of tile
    int soff[5];   // LDS cell offset r*36+s
    #pragma unroll
    for (int k = 0; k < 5; ++k) {
        const int idx = tid + 256 * k;
        const int r = idx / 34, s = idx - r * 34;
        const int gi = row0 - 1 + r, gj = col0 - 1 + s;
        const bool valid = (idx < 1156) && ((unsigned)gi < 128u) && ((unsigned)gj < 128u);
        off[k]  = valid ? (gi * 128 + gj) : -1;
        soff[k] = r * 36 + s;
    }
    const bool has5 = (tid < 132);   // 1156 - 1024
    const float* xb = x + (size_t)(b * 32 + c0) * 16384;

    float acc[OG][4];
    #pragma unroll
    for (int oo = 0; oo < OG; ++oo)
        #pragma unroll
        for (int j = 0; j < 4; ++j) acc[oo][j] = 0.f;

    for (int rd = 0; rd < CG / 2; ++rd) {
        __syncthreads();   // prev round's readers done (also guards ws, rd=0)
        #pragma unroll
        for (int cc = 0; cc < 2; ++cc) {
            const float* xc = xb + (size_t)(2 * rd + cc) * 16384;
            float* xsc = &xs[cc][0][0];
            #pragma unroll
            for (int k = 0; k < 4; ++k) {
                float v = 0.f;
                if (off[k] >= 0) v = xc[off[k]];
                xsc[soff[k]] = v;
            }
            if (has5) {
                float v = 0.f;
                if (off[4] >= 0) v = xc[off[4]];
                xsc[soff[4]] = v;
            }
        }
        __syncthreads();

        #pragma unroll
        for (int cc = 0; cc < 2; ++cc) {
            const int cl = 2 * rd + cc;
            float p[3][6];
            #pragma unroll
            for (int r = 0; r < 3; ++r) {
                const float4 a = *(const float4*)&xs[cc][ty + r][4 * tx];
                const float2 e = *(const float2*)&xs[cc][ty + r][4 * tx + 4];
                p[r][0] = a.x; p[r][1] = a.y; p[r][2] = a.z; p[r][3] = a.w;
                p[r][4] = e.x; p[r][5] = e.y;
            }
            const float4* wrow = (const float4*)&ws[cl * 9][0];
            #pragma unroll
            for (int t = 0; t < 9; ++t) {
                const int r = t / 3;
                const int s = t - r * 3;
                const float4 wv = wrow[t];   // broadcast read, 4 o's
                #pragma unroll
                for (int j = 0; j < 4; ++j) {
                    const float xv = p[r][s + j];
                    acc[0][j] += wv.x * xv;
                    acc[1][j] += wv.y * xv;
                    acc[2][j] += wv.z * xv;
                    acc[3][j] += wv.w * xv;
                }
            }
        }
    }

    const int i  = row0 + ty;
    const int j0 = col0 + 4 * tx;
    #pragma unroll
    for (int oo = 0; oo < OG; ++oo) {
        const int o = og * OG + oo;
        float* dst = &out[(size_t)((b * 32 + o) * 128 + i) * 128 + j0];
        #pragma unroll
        for (int j = 0; j < 4; ++j)
            atomicAdd(dst + j, acc[oo][j]);
    }
}

extern "C" void kernel_launch(void* const* d_in, const int* in_sizes, int n_in,
                              void* d_out, int out_size, void* d_ws, size_t ws_size,
                              hipStream_t stream) {
    const float* x    = (const float*)d_in[0];
    const float* w    = (const float*)d_in[1];
    const float* bias = (const float*)d_in[2];
    float* out = (float*)d_out;

    // out = bias[o] everywhere (also clears the 0xAA poison)
    hipLaunchKernelGGL(init_bias, dim3(2048), dim3(256), 0, stream, bias, out);
    // accumulate conv partials (4 channel-groups per output tile)
    hipLaunchKernelGGL(conv3x3_atomic, dim3(16, 4, 32), dim3(256), 0, stream,
                       x, w, out);
}

// Round 4
// 97.122 us; speedup vs baseline: 2.0045x; 2.0045x over previous
//
#include <hip/hip_runtime.h>

// out[b,o,i,j] = bias[o] + sum_{c,r,s} w[o,c,r,s] * xpad[b,c,i+r,j+s]
// (reference's FFT circular-conv + roll + slice == conv2d pad=1; the
//  frequency-threshold pruning perturbs by ~0.039 absmax < 0.084 threshold)
//
// R4: barrier-free direct conv. R2/R3 falsified the staging-latency and
// occupancy theories; the real killer was the 2-barrier-per-round structure
// (all waves drain vmcnt/lgkmcnt together every round). Now each thread
// loads its own 3x6 patch straight from global (L1 serves the reuse: one
// channel plane tile is ~5 KB), weights broadcast from LDS, ONE barrier
// total, single float4 store per output strip. No atomics, no init pass.

#define OG 4

__global__ __launch_bounds__(256, 2)
void conv3x3_direct(const float* __restrict__ x, const float* __restrict__ w,
                    const float* __restrict__ bias, float* __restrict__ out) {
    const int tid = threadIdx.x;
    const int tx  = tid & 7;    // 4-col strip: cols 4*tx .. 4*tx+3
    const int ty  = tid >> 3;   // row in tile, 0..31
    const int tile = blockIdx.x;        // 4x4 tiles of 32x32
    const int b   = blockIdx.y;
    const int og  = blockIdx.z;
    const int row0 = (tile >> 2) << 5;
    const int col0 = (tile & 3) << 5;

    __shared__ __align__(16) float ws[32 * 9][OG];   // [c*9+t][oo]
    for (int idx = tid; idx < 32 * 9 * OG; idx += 256) {   // 1152
        const int k  = idx >> 2;
        const int oo = idx & 3;
        const int c  = k / 9;
        const int t  = k - 9 * c;
        ws[k][oo] = w[((og * OG + oo) * 32 + c) * 9 + t];
    }
    __syncthreads();   // the only barrier

    const int i  = row0 + ty;        // output row
    const int j0 = col0 + 4 * tx;    // first output col (multiple of 4 -> f4 aligned)

    // channel-invariant geometry: 3 input rows (clamped + validity), edge cols
    const float* xb = x + (size_t)b * 32 * 16384;
    int  roff[3];
    bool rvalid[3];
    #pragma unroll
    for (int r = 0; r < 3; ++r) {
        const int gi = i - 1 + r;
        rvalid[r] = (unsigned)gi < 128u;
        roff[r]   = min(max(gi, 0), 127) * 128;
    }
    const bool lval = (j0 - 1) >= 0;
    const bool rval = (j0 + 4) < 128;
    const int  jl   = max(j0 - 1, 0);
    const int  jr   = min(j0 + 4, 127);

    float acc[OG][4];
    #pragma unroll
    for (int oo = 0; oo < OG; ++oo)
        #pragma unroll
        for (int j = 0; j < 4; ++j) acc[oo][j] = 0.f;

    #pragma unroll 4
    for (int c = 0; c < 32; ++c) {
        const float* xc = xb + c * 16384;
        float p[3][6];
        #pragma unroll
        for (int r = 0; r < 3; ++r) {
            const float4 a  = *(const float4*)(xc + roff[r] + j0);
            const float  lf = xc[roff[r] + jl];
            const float  rt = xc[roff[r] + jr];
            const bool v = rvalid[r];
            p[r][0] = (v && lval) ? lf  : 0.f;
            p[r][1] = v ? a.x : 0.f;
            p[r][2] = v ? a.y : 0.f;
            p[r][3] = v ? a.z : 0.f;
            p[r][4] = v ? a.w : 0.f;
            p[r][5] = (v && rval) ? rt  : 0.f;
        }
        const float4* wrow = (const float4*)&ws[c * 9][0];
        #pragma unroll
        for (int t = 0; t < 9; ++t) {
            const int r = t / 3;
            const int s = t - r * 3;
            const float4 wv = wrow[t];   // broadcast ds_read_b128, 4 o's
            #pragma unroll
            for (int j = 0; j < 4; ++j) {
                const float xv = p[r][s + j];
                acc[0][j] += wv.x * xv;
                acc[1][j] += wv.y * xv;
                acc[2][j] += wv.z * xv;
                acc[3][j] += wv.w * xv;
            }
        }
    }

    #pragma unroll
    for (int oo = 0; oo < OG; ++oo) {
        const int o = og * OG + oo;
        const float bv = bias[o];
        float4 res;
        res.x = acc[oo][0] + bv;
        res.y = acc[oo][1] + bv;
        res.z = acc[oo][2] + bv;
        res.w = acc[oo][3] + bv;
        *(float4*)&out[(size_t)((b * 32 + o) * 128 + i) * 128 + j0] = res;
    }
}

extern "C" void kernel_launch(void* const* d_in, const int* in_sizes, int n_in,
                              void* d_out, int out_size, void* d_ws, size_t ws_size,
                              hipStream_t stream) {
    const float* x    = (const float*)d_in[0];
    const float* w    = (const float*)d_in[1];
    const float* bias = (const float*)d_in[2];
    float* out = (float*)d_out;
    hipLaunchKernelGGL(conv3x3_direct, dim3(16, 4, 8), dim3(256), 0, stream,
                       x, w, bias, out);
}

// Round 5
// 77.817 us; speedup vs baseline: 2.5018x; 1.2481x over previous
//
#include <hip/hip_runtime.h>

// out[b,o,i,j] = bias[o] + sum_{c,r,s} w[o,c,r,s] * xpad[b,c,i+r,j+s]
// (reference's FFT circular-conv + roll + slice == conv2d pad=1; pruning
//  deviation ~0.039 + bf16 rounding ~0.012 < 0.084 threshold)
//
// R5: bf16 MFMA implicit GEMM. M=32 (o), N=65536 (pixels), K=288 = 9 taps x
// 32 channels -> mfma_f32_16x16x32_bf16, one K-chunk per tap. Kernel 1
// transposes x to channels-last bf16 (B-frag = one 16B load); kernel 2 preps
// weights wt[t][o][c]; kernel 3: per wave one 16-pixel group x 32 o's,
// A-frags in registers, 9 B-loads + 18 MFMAs, no LDS, no barriers.

typedef __attribute__((ext_vector_type(8))) short short8;
typedef __attribute__((ext_vector_type(4))) float f32x4;
typedef __attribute__((ext_vector_type(4))) unsigned int u32x4;

__device__ __forceinline__ unsigned short f2bf(float f) {
    unsigned int u = __builtin_bit_cast(unsigned int, f);
    u += 0x7FFFu + ((u >> 16) & 1u);          // round-to-nearest-even
    return (unsigned short)(u >> 16);
}

// x (4,32,128,128) fp32 NCHW  ->  xt (4,16384,32) bf16 channels-last
__global__ __launch_bounds__(256)
void transpose_x(const float* __restrict__ x, unsigned short* __restrict__ xt) {
    const int pg = blockIdx.x * 256 + threadIdx.x;   // [0, 65536) = b*16384+px
    const int b  = pg >> 14;
    const int px = pg & 16383;
    const float* xp = x + (size_t)b * 32 * 16384 + px;
    unsigned int u[16];
    #pragma unroll
    for (int cp = 0; cp < 16; ++cp) {
        const float f0 = xp[(size_t)(2 * cp)     * 16384];
        const float f1 = xp[(size_t)(2 * cp + 1) * 16384];
        u[cp] = (unsigned)f2bf(f0) | ((unsigned)f2bf(f1) << 16);
    }
    u32x4* dst = (u32x4*)(xt + (size_t)pg * 32);     // 64B contiguous per lane
    #pragma unroll
    for (int q = 0; q < 4; ++q) {
        u32x4 v;
        v[0] = u[4*q]; v[1] = u[4*q+1]; v[2] = u[4*q+2]; v[3] = u[4*q+3];
        dst[q] = v;
    }
}

// w (32,32,3,3) fp32 -> wt[(t*32 + o)*32 + c] bf16, t = r*3+s
__global__ void transpose_w(const float* __restrict__ w, unsigned short* __restrict__ wt) {
    const int idx = blockIdx.x * 256 + threadIdx.x;  // < 9216
    if (idx < 9216) {
        const int t = idx >> 10;
        const int o = (idx >> 5) & 31;
        const int c = idx & 31;
        wt[idx] = f2bf(w[(o * 32 + c) * 9 + t]);
    }
}

__global__ __launch_bounds__(256, 4)
void conv_mfma(const unsigned short* __restrict__ xt,
               const unsigned short* __restrict__ wt,
               const float* __restrict__ bias,
               float* __restrict__ out) {
    const int tid  = threadIdx.x;
    const int wave = tid >> 6;
    const int lane = tid & 63;
    const int lm   = lane & 15;     // n: pixel within group / m: o within tile
    const int quad = lane >> 4;
    const int q8   = quad * 8;      // k-subrange base (channel)

    const int g  = blockIdx.x * 4 + wave;   // pixel group id, [0, 4096)
    const int b  = g >> 10;
    const int i  = (g >> 3) & 127;
    const int j0 = (g & 7) * 16;
    const int j  = j0 + lm;

    // A-frags: A[m=lane&15][k=quad*8+jj] ; value = w[o=mt*16+lm][c=q8+jj][tap t]
    u32x4 af[9][2];
    #pragma unroll
    for (int t = 0; t < 9; ++t)
        #pragma unroll
        for (int mt = 0; mt < 2; ++mt)
            af[t][mt] = *(const u32x4*)(wt + ((t * 32 + mt * 16 + lm) * 32 + q8));

    f32x4 acc0 = {0.f, 0.f, 0.f, 0.f};
    f32x4 acc1 = {0.f, 0.f, 0.f, 0.f};
    const unsigned short* xb = xt + (size_t)b * 16384 * 32;

    #pragma unroll
    for (int t = 0; t < 9; ++t) {
        const int r  = t / 3, s = t - 3 * r;
        const int si = i + r - 1;               // group-uniform
        const int sj = j + s - 1;               // per-lane (edges only)
        const bool ok = ((unsigned)si < 128u) && ((unsigned)sj < 128u);
        const int ci = min(max(si, 0), 127);
        const int cj = min(max(sj, 0), 127);
        // B-frag: B[k=q8+jj][n=lm] = xt[b][src_pix][c=q8+jj] -- one 16B load
        u32x4 bv = *(const u32x4*)(xb + ((size_t)(ci * 128 + cj) * 32 + q8));
        const unsigned msk = ok ? 0xFFFFFFFFu : 0u;
        bv &= msk;                              // zero-pad outside image
        const short8 bs = __builtin_bit_cast(short8, bv);
        acc0 = __builtin_amdgcn_mfma_f32_16x16x32_bf16(
                   __builtin_bit_cast(short8, af[t][0]), bs, acc0, 0, 0, 0);
        acc1 = __builtin_amdgcn_mfma_f32_16x16x32_bf16(
                   __builtin_bit_cast(short8, af[t][1]), bs, acc1, 0, 0, 0);
    }

    // D: col = lane&15 = pixel, row = quad*4+reg = o within 16-tile
    const size_t pixbase = (size_t)i * 128 + j0 + lm;
    #pragma unroll
    for (int reg = 0; reg < 4; ++reg) {
        const int o0 = quad * 4 + reg;          // m-tile 0
        const int o1 = 16 + o0;                 // m-tile 1
        out[((size_t)(b * 32 + o0) << 14) + pixbase] = acc0[reg] + bias[o0];
        out[((size_t)(b * 32 + o1) << 14) + pixbase] = acc1[reg] + bias[o1];
    }
}

extern "C" void kernel_launch(void* const* d_in, const int* in_sizes, int n_in,
                              void* d_out, int out_size, void* d_ws, size_t ws_size,
                              hipStream_t stream) {
    const float* x    = (const float*)d_in[0];
    const float* w    = (const float*)d_in[1];
    const float* bias = (const float*)d_in[2];
    float* out = (float*)d_out;

    unsigned short* xt = (unsigned short*)d_ws;                       // 4 MiB
    unsigned short* wt = (unsigned short*)((char*)d_ws + (4 << 20));  // 18 KiB

    hipLaunchKernelGGL(transpose_x, dim3(256), dim3(256), 0, stream, x, xt);
    hipLaunchKernelGGL(transpose_w, dim3(36),  dim3(256), 0, stream, w, wt);
    hipLaunchKernelGGL(conv_mfma,   dim3(1024), dim3(256), 0, stream,
                       xt, wt, bias, out);
}

// Round 6
// 76.155 us; speedup vs baseline: 2.5564x; 1.0218x over previous
//
#include <hip/hip_runtime.h>

// out[b,o,i,j] = bias[o] + sum_{c,r,s} w[o,c,r,s] * xpad[b,c,i+r,j+s]
// (reference's FFT circular-conv + roll + slice == conv2d pad=1; pruning
//  deviation + bf16 rounding = 0.033 absmax < 0.084 threshold)
//
// R6: prep-pipeline shave. Timed window contains a fixed ~50 us harness
// poison-fill of d_ws/d_out (268 MB @ 77% HBM peak — not removable), so the
// addressable part is our ~28 us. Transpose parallelism x4 (1024 blocks,
// 8 channels/thread, dense lines both ways), w-prep fused into same launch.
// conv_mfma (R5, verified) unchanged: 16-pixel group x 32 o's per wave,
// 9 B-loads + 18 MFMAs, no LDS, no barriers.

typedef __attribute__((ext_vector_type(8))) short short8;
typedef __attribute__((ext_vector_type(4))) float f32x4;
typedef __attribute__((ext_vector_type(4))) unsigned int u32x4;

__device__ __forceinline__ unsigned short f2bf(float f) {
    unsigned int u = __builtin_bit_cast(unsigned int, f);
    u += 0x7FFFu + ((u >> 16) & 1u);          // round-to-nearest-even
    return (unsigned short)(u >> 16);
}

// blocks 0..1023: x (4,32,128,128) fp32 NCHW -> xt (4,16384,32) bf16
//                 (thread = 8 channels of one pixel-group; 16B store/lane)
// block  1024   : w (32,32,3,3) fp32 -> wt[(t*32+o)*32+c] bf16
__global__ __launch_bounds__(256)
void prep(const float* __restrict__ x, const float* __restrict__ w,
          unsigned short* __restrict__ xt, unsigned short* __restrict__ wt) {
    const int blk = blockIdx.x;
    const int tid = threadIdx.x;
    if (blk < 1024) {
        const int idx = blk * 256 + tid;      // [0, 262144)
        const int pg  = idx >> 2;             // b*16384 + px
        const int q   = idx & 3;              // channel octet
        const int b   = pg >> 14;
        const int px  = pg & 16383;
        const float* xp = x + ((size_t)(b * 32 + q * 8) << 14) + px;
        unsigned int u[4];
        #pragma unroll
        for (int cp = 0; cp < 4; ++cp) {
            const float f0 = xp[(size_t)(2 * cp) << 14];
            const float f1 = xp[(size_t)(2 * cp + 1) << 14];
            u[cp] = (unsigned)f2bf(f0) | ((unsigned)f2bf(f1) << 16);
        }
        u32x4 v; v[0] = u[0]; v[1] = u[1]; v[2] = u[2]; v[3] = u[3];
        *(u32x4*)(xt + (size_t)pg * 32 + q * 8) = v;
    } else {
        for (int idx = tid; idx < 9216; idx += 256) {
            const int t = idx >> 10;
            const int o = (idx >> 5) & 31;
            const int c = idx & 31;
            wt[idx] = f2bf(w[(o * 32 + c) * 9 + t]);
        }
    }
}

__global__ __launch_bounds__(256, 4)
void conv_mfma(const unsigned short* __restrict__ xt,
               const unsigned short* __restrict__ wt,
               const float* __restrict__ bias,
               float* __restrict__ out) {
    const int tid  = threadIdx.x;
    const int wave = tid >> 6;
    const int lane = tid & 63;
    const int lm   = lane & 15;     // n: pixel within group / m: o within tile
    const int quad = lane >> 4;
    const int q8   = quad * 8;      // k-subrange base (channel)

    const int g  = blockIdx.x * 4 + wave;   // pixel group id, [0, 4096)
    const int b  = g >> 10;
    const int i  = (g >> 3) & 127;
    const int j0 = (g & 7) * 16;
    const int j  = j0 + lm;

    // A-frags: A[m=lane&15][k=quad*8+jj] ; value = w[o=mt*16+lm][c=q8+jj][tap t]
    u32x4 af[9][2];
    #pragma unroll
    for (int t = 0; t < 9; ++t)
        #pragma unroll
        for (int mt = 0; mt < 2; ++mt)
            af[t][mt] = *(const u32x4*)(wt + ((t * 32 + mt * 16 + lm) * 32 + q8));

    f32x4 acc0 = {0.f, 0.f, 0.f, 0.f};
    f32x4 acc1 = {0.f, 0.f, 0.f, 0.f};
    const unsigned short* xb = xt + (size_t)b * 16384 * 32;

    #pragma unroll
    for (int t = 0; t < 9; ++t) {
        const int r  = t / 3, s = t - 3 * r;
        const int si = i + r - 1;               // group-uniform
        const int sj = j + s - 1;               // per-lane (edges only)
        const bool ok = ((unsigned)si < 128u) && ((unsigned)sj < 128u);
        const int ci = min(max(si, 0), 127);
        const int cj = min(max(sj, 0), 127);
        // B-frag: B[k=q8+jj][n=lm] = xt[b][src_pix][c=q8+jj] -- one 16B load
        u32x4 bv = *(const u32x4*)(xb + ((size_t)(ci * 128 + cj) * 32 + q8));
        const unsigned msk = ok ? 0xFFFFFFFFu : 0u;
        bv &= msk;                              // zero-pad outside image
        const short8 bs = __builtin_bit_cast(short8, bv);
        acc0 = __builtin_amdgcn_mfma_f32_16x16x32_bf16(
                   __builtin_bit_cast(short8, af[t][0]), bs, acc0, 0, 0, 0);
        acc1 = __builtin_amdgcn_mfma_f32_16x16x32_bf16(
                   __builtin_bit_cast(short8, af[t][1]), bs, acc1, 0, 0, 0);
    }

    // D: col = lane&15 = pixel, row = quad*4+reg = o within 16-tile
    const size_t pixbase = (size_t)i * 128 + j0 + lm;
    #pragma unroll
    for (int reg = 0; reg < 4; ++reg) {
        const int o0 = quad * 4 + reg;          // m-tile 0
        const int o1 = 16 + o0;                 // m-tile 1
        out[((size_t)(b * 32 + o0) << 14) + pixbase] = acc0[reg] + bias[o0];
        out[((size_t)(b * 32 + o1) << 14) + pixbase] = acc1[reg] + bias[o1];
    }
}

extern "C" void kernel_launch(void* const* d_in, const int* in_sizes, int n_in,
                              void* d_out, int out_size, void* d_ws, size_t ws_size,
                              hipStream_t stream) {
    const float* x    = (const float*)d_in[0];
    const float* w    = (const float*)d_in[1];
    const float* bias = (const float*)d_in[2];
    float* out = (float*)d_out;

    unsigned short* xt = (unsigned short*)d_ws;                       // 4 MiB
    unsigned short* wt = (unsigned short*)((char*)d_ws + (4 << 20));  // 18 KiB

    hipLaunchKernelGGL(prep,      dim3(1025), dim3(256), 0, stream, x, w, xt, wt);
    hipLaunchKernelGGL(conv_mfma, dim3(1024), dim3(256), 0, stream,
                       xt, wt, bias, out);
}

// Round 7
// 73.963 us; speedup vs baseline: 2.6321x; 1.0296x over previous
//
#include <hip/hip_runtime.h>

// out[b,o,i,j] = bias[o] + sum_{c,r,s} w[o,c,r,s] * xpad[b,c,i+r,j+s]
// (reference's FFT circular-conv + roll + slice == conv2d pad=1; pruning
//  deviation + bf16 rounding = 0.033 absmax < 0.084 threshold)
//
// R7: kill the prep straggler. R6 put w-prep in ONE block with 36 rolled
// serialized rounds (~7 us tail gating the whole dispatch). Now w-prep is
// 36 blocks x 1 element/thread. x-transpose (1024 blocks) and conv_mfma
// (R5-verified: 16-pixel group x 32 o's per wave, 9 B-loads + 18 MFMAs,
// no LDS, no barriers) unchanged. Timed window is otherwise dominated by
// the harness 268 MB d_ws poison fill (~44 us @ 77% HBM peak, fixed).

typedef __attribute__((ext_vector_type(8))) short short8;
typedef __attribute__((ext_vector_type(4))) float f32x4;
typedef __attribute__((ext_vector_type(4))) unsigned int u32x4;

__device__ __forceinline__ unsigned short f2bf(float f) {
    unsigned int u = __builtin_bit_cast(unsigned int, f);
    u += 0x7FFFu + ((u >> 16) & 1u);          // round-to-nearest-even
    return (unsigned short)(u >> 16);
}

// blocks 0..1023 : x (4,32,128,128) fp32 NCHW -> xt (4,16384,32) bf16
// blocks 1024..1059: w (32,32,3,3) fp32 -> wt[(t*32+o)*32+c] bf16 (1 elt/thread)
__global__ __launch_bounds__(256)
void prep(const float* __restrict__ x, const float* __restrict__ w,
          unsigned short* __restrict__ xt, unsigned short* __restrict__ wt) {
    const int blk = blockIdx.x;
    const int tid = threadIdx.x;
    if (blk < 1024) {
        const int idx = blk * 256 + tid;      // [0, 262144)
        const int pg  = idx >> 2;             // b*16384 + px
        const int q   = idx & 3;              // channel octet
        const int b   = pg >> 14;
        const int px  = pg & 16383;
        const float* xp = x + ((size_t)(b * 32 + q * 8) << 14) + px;
        unsigned int u[4];
        #pragma unroll
        for (int cp = 0; cp < 4; ++cp) {
            const float f0 = xp[(size_t)(2 * cp) << 14];
            const float f1 = xp[(size_t)(2 * cp + 1) << 14];
            u[cp] = (unsigned)f2bf(f0) | ((unsigned)f2bf(f1) << 16);
        }
        u32x4 v; v[0] = u[0]; v[1] = u[1]; v[2] = u[2]; v[3] = u[3];
        *(u32x4*)(xt + (size_t)pg * 32 + q * 8) = v;
    } else {
        const int idx = (blk - 1024) * 256 + tid;   // [0, 9216)
        const int t = idx >> 10;
        const int o = (idx >> 5) & 31;
        const int c = idx & 31;
        wt[idx] = f2bf(w[(o * 32 + c) * 9 + t]);
    }
}

__global__ __launch_bounds__(256, 4)
void conv_mfma(const unsigned short* __restrict__ xt,
               const unsigned short* __restrict__ wt,
               const float* __restrict__ bias,
               float* __restrict__ out) {
    const int tid  = threadIdx.x;
    const int wave = tid >> 6;
    const int lane = tid & 63;
    const int lm   = lane & 15;     // n: pixel within group / m: o within tile
    const int quad = lane >> 4;
    const int q8   = quad * 8;      // k-subrange base (channel)

    const int g  = blockIdx.x * 4 + wave;   // pixel group id, [0, 4096)
    const int b  = g >> 10;
    const int i  = (g >> 3) & 127;
    const int j0 = (g & 7) * 16;
    const int j  = j0 + lm;

    // A-frags: A[m=lane&15][k=quad*8+jj] ; value = w[o=mt*16+lm][c=q8+jj][tap t]
    u32x4 af[9][2];
    #pragma unroll
    for (int t = 0; t < 9; ++t)
        #pragma unroll
        for (int mt = 0; mt < 2; ++mt)
            af[t][mt] = *(const u32x4*)(wt + ((t * 32 + mt * 16 + lm) * 32 + q8));

    f32x4 acc0 = {0.f, 0.f, 0.f, 0.f};
    f32x4 acc1 = {0.f, 0.f, 0.f, 0.f};
    const unsigned short* xb = xt + (size_t)b * 16384 * 32;

    #pragma unroll
    for (int t = 0; t < 9; ++t) {
        const int r  = t / 3, s = t - 3 * r;
        const int si = i + r - 1;               // group-uniform
        const int sj = j + s - 1;               // per-lane (edges only)
        const bool ok = ((unsigned)si < 128u) && ((unsigned)sj < 128u);
        const int ci = min(max(si, 0), 127);
        const int cj = min(max(sj, 0), 127);
        // B-frag: B[k=q8+jj][n=lm] = xt[b][src_pix][c=q8+jj] -- one 16B load
        u32x4 bv = *(const u32x4*)(xb + ((size_t)(ci * 128 + cj) * 32 + q8));
        const unsigned msk = ok ? 0xFFFFFFFFu : 0u;
        bv &= msk;                              // zero-pad outside image
        const short8 bs = __builtin_bit_cast(short8, bv);
        acc0 = __builtin_amdgcn_mfma_f32_16x16x32_bf16(
                   __builtin_bit_cast(short8, af[t][0]), bs, acc0, 0, 0, 0);
        acc1 = __builtin_amdgcn_mfma_f32_16x16x32_bf16(
                   __builtin_bit_cast(short8, af[t][1]), bs, acc1, 0, 0, 0);
    }

    // D: col = lane&15 = pixel, row = quad*4+reg = o within 16-tile
    const size_t pixbase = (size_t)i * 128 + j0 + lm;
    #pragma unroll
    for (int reg = 0; reg < 4; ++reg) {
        const int o0 = quad * 4 + reg;          // m-tile 0
        const int o1 = 16 + o0;                 // m-tile 1
        out[((size_t)(b * 32 + o0) << 14) + pixbase] = acc0[reg] + bias[o0];
        out[((size_t)(b * 32 + o1) << 14) + pixbase] = acc1[reg] + bias[o1];
    }
}

extern "C" void kernel_launch(void* const* d_in, const int* in_sizes, int n_in,
                              void* d_out, int out_size, void* d_ws, size_t ws_size,
                              hipStream_t stream) {
    const float* x    = (const float*)d_in[0];
    const float* w    = (const float*)d_in[1];
    const float* bias = (const float*)d_in[2];
    float* out = (float*)d_out;

    unsigned short* xt = (unsigned short*)d_ws;                       // 4 MiB
    unsigned short* wt = (unsigned short*)((char*)d_ws + (4 << 20));  // 18 KiB

    hipLaunchKernelGGL(prep,      dim3(1060), dim3(256), 0, stream, x, w, xt, wt);
    hipLaunchKernelGGL(conv_mfma, dim3(1024), dim3(256), 0, stream,
                       xt, wt, bias, out);
}